// Round 10
// baseline (590.735 us; speedup 1.0000x reference)
//
#include <hip/hip_runtime.h>
#include <hip/hip_bf16.h>

#define BATCH   16384
#define IN_F    1024
#define OUT_F   1024
#define KCOLS   11
#define KPL     12          // 11 basis planes + 1 x-plane (for W)
#define KP      (KPL*IN_F)  // 12288
#define KHALF   (KP/2)      // 6144 per split-K block
#define NT      (KHALF/32)  // 192 K-tiles of 32 per half
#define LN_EPS  1e-5f

typedef __attribute__((ext_vector_type(8))) short short8;
typedef __attribute__((ext_vector_type(4))) float f32x4;

static __device__ __forceinline__ unsigned short f2bf(float f) {
  __hip_bfloat16 h = __float2bfloat16(f);
  return *reinterpret_cast<unsigned short*>(&h);
}

// Cox-de Boor, faithful to the reference's in-place variant.
__device__ __forceinline__ void bspline_basis(float x, float bas[KCOLS]) {
  const float s = 1.0f / 11.0f;
  float kn[12];
#pragma unroll
  for (int j = 0; j < 12; ++j) kn[j] = (float)j * s;
  kn[11] = 1.0f;
#pragma unroll
  for (int j = 0; j < 11; ++j)
    bas[j] = (x >= kn[j] && x < kn[j + 1]) ? 1.0f : 0.0f;
#pragma unroll
  for (int d = 1; d <= 3; ++d) {
#pragma unroll
    for (int j = 0; j < 11 - d; ++j) {
      const float r1 = 1.0f / (kn[j + d] - kn[j]);
      const float r2 = 1.0f / (kn[j + d + 1] - kn[j + 1]);
      float a = (x - kn[j]) * r1;
      float c = (kn[j + d + 1] - x) * r2;
      bas[j] = a * bas[j] + c * bas[j + 1];
    }
  }
}

// A[localRow][k*1024 + i] (bf16): 11 basis planes + x plane.
__global__ __launch_bounds__(256) void featgen(const float* __restrict__ X,
                                               unsigned short* __restrict__ A,
                                               int row0) {
  const int brow = blockIdx.x;
  const int i0 = threadIdx.x * 4;
  const float4 xv = *reinterpret_cast<const float4*>(X + (size_t)(row0 + brow) * IN_F + i0);
  float xs[4] = {xv.x, xv.y, xv.z, xv.w};
  float bas[4][KCOLS];
#pragma unroll
  for (int t = 0; t < 4; ++t) bspline_basis(xs[t], bas[t]);
  unsigned short* outp = A + (size_t)brow * KP + i0;
#pragma unroll
  for (int k = 0; k < KCOLS; ++k) {
    ushort4 u;
    u.x = f2bf(bas[0][k]); u.y = f2bf(bas[1][k]);
    u.z = f2bf(bas[2][k]); u.w = f2bf(bas[3][k]);
    *reinterpret_cast<ushort4*>(outp + (size_t)k * IN_F) = u;
  }
  ushort4 u;
  u.x = f2bf(xs[0]); u.y = f2bf(xs[1]); u.z = f2bf(xs[2]); u.w = f2bf(xs[3]);
  *reinterpret_cast<ushort4*>(outp + (size_t)KCOLS * IN_F) = u;
}

// Bmat[o][k*1024 + i] (bf16): cp planes + W plane.
__global__ __launch_bounds__(256) void bgen(const float* __restrict__ CP,
                                            const float* __restrict__ W,
                                            unsigned short* __restrict__ Bm) {
  const int o = blockIdx.x;
  const int i0 = threadIdx.x * 4;
  unsigned short* outp = Bm + (size_t)o * KP + i0;
#pragma unroll
  for (int k = 0; k < KCOLS; ++k) {
    ushort4 u;
    u.x = f2bf(CP[((size_t)o * IN_F + i0 + 0) * KCOLS + k]);
    u.y = f2bf(CP[((size_t)o * IN_F + i0 + 1) * KCOLS + k]);
    u.z = f2bf(CP[((size_t)o * IN_F + i0 + 2) * KCOLS + k]);
    u.w = f2bf(CP[((size_t)o * IN_F + i0 + 3) * KCOLS + k]);
    *reinterpret_cast<ushort4*>(outp + (size_t)k * IN_F) = u;
  }
  ushort4 u;
  u.x = f2bf(W[(size_t)o * IN_F + i0 + 0]);
  u.y = f2bf(W[(size_t)o * IN_F + i0 + 1]);
  u.z = f2bf(W[(size_t)o * IN_F + i0 + 2]);
  u.w = f2bf(W[(size_t)o * IN_F + i0 + 3]);
  *reinterpret_cast<ushort4*>(outp + (size_t)KCOLS * IN_F) = u;
}

// ---- 256x128 split-K GEMM, BK=32, triple-buffered, 2 blocks/CU -------------
// ks=0 -> Cc, ks=1 -> Cp. Grid = nbm*16; 8192 rows -> 512 WGs = 2 blocks/CU.
// 512 thr = 8 waves (2M x 4N); per wave 128x32 out (8 Mtiles x 2 Ntiles).
// LDS 72 KiB = 3 bufs x (A 256x32 + B 128x32). Staging 3 issues/tile (A2,B1),
// 2-tile lookahead, WAITV(3) once per iter drains exactly tile t+1.
// 32-col tiles: 64-B rows -> swizzle chunk ^= (row>>1)&3 (2-way free reads);
// staging source carries the inverse (linear LDS dest).

#define BAR()    __builtin_amdgcn_s_barrier()
#define SCHED0() __builtin_amdgcn_sched_barrier(0)
#define WAITV(N) asm volatile("s_waitcnt vmcnt(" #N ")" ::: "memory")

__global__ __launch_bounds__(512, 4) void gemmk(const unsigned short* __restrict__ A,
                                                const unsigned short* __restrict__ Bm,
                                                float* __restrict__ Cc,
                                                float* __restrict__ Cp, int nbm) {
  __shared__ unsigned short ldsA[3][256 * 32];   // 3 x 16 KiB
  __shared__ unsigned short ldsB[3][128 * 32];   // 3 x 8 KiB
  const int tid  = (int)threadIdx.x;
  const int lane = tid & 63;
  const int w    = tid >> 6;
  const int wm   = w >> 2;       // 0..1
  const int wn   = w & 3;        // 0..3

  // XCD-aware bijective swizzle; per-XCD chunk groups {bm} x {ks} x {bn}.
  const int nwg = nbm * 16;
  const int cpx = nwg >> 3;
  const int bid = (int)blockIdx.x;
  const int swz = (bid & 7) * cpx + (bid >> 3);
  const int bn = swz & 7;
  const int ks = (swz >> 3) & 1;
  const int bm = swz >> 4;
  const size_t koff = (size_t)ks * KHALF;
  float* __restrict__ C = ks ? Cp : Cc;

  // staging: one issue = 512 thr x 16 B = 128 rows x 32 cols (8 KiB).
  // thread t: row = t>>2, dest chunk = t&3; source chunk = (t&3) ^ ((t>>3)&3).
  const int srow = tid >> 2;                       // 0..127
  const int schunk = (tid & 3) ^ ((tid >> 3) & 3); // inverse swizzle
  const unsigned short* aSrc = A  + (size_t)(bm * 256 + srow) * KP + koff + schunk * 8;
  const unsigned short* bSrc = Bm + (size_t)(bn * 128 + srow) * KP + koff + schunk * 8;

#define STAGE_A(T, ISS, BUF)                                                          \
  do {                                                                                \
    if ((T) < NT) {                                                                   \
      const unsigned short* g_ = aSrc + (size_t)(ISS) * 128 * KP + (size_t)(T) * 32;  \
      __builtin_amdgcn_global_load_lds((const __attribute__((address_space(1))) void*)g_, \
          (__attribute__((address_space(3))) void*)(&ldsA[BUF][(ISS) * 4096 + w * 512]), 16, 0, 0); \
    }                                                                                 \
  } while (0)

#define STAGE_B(T, BUF)                                                               \
  do {                                                                               \
    if ((T) < NT) {                                                                   \
      const unsigned short* g_ = bSrc + (size_t)(T) * 32;                             \
      __builtin_amdgcn_global_load_lds((const __attribute__((address_space(1))) void*)g_, \
          (__attribute__((address_space(3))) void*)(&ldsB[BUF][w * 512]), 16, 0, 0);  \
    }                                                                                 \
  } while (0)

  // fragment reads: lane reads row (tile*16 + fr), elems chunk g4 (g4 = lane>>4
  // in 0..3 covers k 0..31); swizzled col = (g4 ^ ((fr>>1)&3)) * 8 elements.
  const int fr = lane & 15;
  const int g4 = lane >> 4;
  const int colx = ((g4 ^ ((fr >> 1) & 3)) << 3);

  short8 aF[4], bF[2];
  f32x4 acc[8][2] = {};

#define LOADA4(MB, BUF)                                                        \
  do {                                                                         \
    _Pragma("unroll") for (int m_ = 0; m_ < 4; ++m_)                           \
      aF[m_] = *reinterpret_cast<const short8*>(                               \
          &ldsA[BUF][(wm * 128 + ((MB) + m_) * 16 + fr) * 32 + colx]);         \
  } while (0)

#define LOADB2(BUF)                                                            \
  do {                                                                         \
    _Pragma("unroll") for (int n_ = 0; n_ < 2; ++n_)                           \
      bF[n_] = *reinterpret_cast<const short8*>(                               \
          &ldsB[BUF][(wn * 32 + n_ * 16 + fr) * 32 + colx]);                   \
  } while (0)

#define MFMAH(MB)                                                              \
  do {                                                                         \
    __builtin_amdgcn_s_setprio(1);                                             \
    _Pragma("unroll") for (int m_ = 0; m_ < 4; ++m_)                           \
    _Pragma("unroll") for (int n_ = 0; n_ < 2; ++n_)                           \
      acc[(MB) + m_][n_] = __builtin_amdgcn_mfma_f32_16x16x32_bf16(            \
          aF[m_], bF[n_], acc[(MB) + m_][n_], 0, 0, 0);                        \
    __builtin_amdgcn_s_setprio(0);                                             \
  } while (0)

  // one iteration (tile T in buffer CUR; stage tile T+2 into buffer NX2)
#define ITER(T, CUR, NX2)                                                      \
  do {                                                                         \
    /* Ph1: m0-3 x n0-1; stage A(T+2) */                                       \
    LOADB2(CUR); LOADA4(0, CUR);                                               \
    STAGE_A((T) + 2, 0, NX2); STAGE_A((T) + 2, 1, NX2);                        \
    MFMAH(0);                                                                  \
    SCHED0(); BAR();                                                           \
    /* Ph2: m4-7 (bF persists); stage B(T+2); drain tile T+1 */                \
    LOADA4(4, CUR);                                                            \
    STAGE_B((T) + 2, NX2);                                                     \
    MFMAH(4);                                                                  \
    if ((T) < NT - 2) { WAITV(3); } else { WAITV(0); }                         \
    SCHED0(); BAR();                                                           \
  } while (0)

  // prologue: stage tile0 (A0,A1,B) and tile1; drain tile0 (leave tile1's 3).
  STAGE_A(0, 0, 0); STAGE_A(0, 1, 0); STAGE_B(0, 0);
  STAGE_A(1, 0, 1); STAGE_A(1, 1, 1); STAGE_B(1, 1);
  WAITV(3);
  BAR();

#pragma unroll 1
  for (int jg = 0; jg < NT / 3; ++jg) {
    const int t0 = jg * 3;
    ITER(t0 + 0, 0, 2);
    ITER(t0 + 1, 1, 0);
    ITER(t0 + 2, 2, 1);
  }

  // C/D layout (verified m89/m91): col = lane&15, row = (lane>>4)*4 + reg
  const size_t r0 = (size_t)bm * 256 + wm * 128 + (lane >> 4) * 4;
  const int c0 = bn * 128 + wn * 32 + fr;
#pragma unroll
  for (int m = 0; m < 8; ++m)
#pragma unroll
    for (int n = 0; n < 2; ++n)
#pragma unroll
      for (int r = 0; r < 4; ++r)
        C[(r0 + m * 16 + r) * OUT_F + (c0 + n * 16)] = acc[m][n][r];
}

// Row LayerNorm over C0+C1+bias, written in place to C0.
__global__ __launch_bounds__(256) void ln_kernel(float* __restrict__ C,
                                                 const float* __restrict__ P,
                                                 const float* __restrict__ bias,
                                                 const float* __restrict__ gamma,
                                                 const float* __restrict__ beta) {
  const int row = blockIdx.x;
  const int tid = threadIdx.x;
  float4 v = *reinterpret_cast<const float4*>(C + (size_t)row * OUT_F + tid * 4);
  const float4 p = *reinterpret_cast<const float4*>(P + (size_t)row * OUT_F + tid * 4);
  const float4 bb = *reinterpret_cast<const float4*>(bias + tid * 4);
  v.x += p.x + bb.x; v.y += p.y + bb.y; v.z += p.z + bb.z; v.w += p.w + bb.w;
  float s = v.x + v.y + v.z + v.w;
  float q = v.x * v.x + v.y * v.y + v.z * v.z + v.w * v.w;
#pragma unroll
  for (int off = 32; off > 0; off >>= 1) {
    s += __shfl_down(s, off);
    q += __shfl_down(q, off);
  }
  __shared__ float red[8];
  const int wave = tid >> 6, lane = tid & 63;
  if (lane == 0) { red[wave] = s; red[4 + wave] = q; }
  __syncthreads();
  s = red[0] + red[1] + red[2] + red[3];
  q = red[4] + red[5] + red[6] + red[7];
  const float mu = s * (1.0f / OUT_F);
  const float var = q * (1.0f / OUT_F) - mu * mu;
  const float rs = rsqrtf(var + LN_EPS);
  const float4 g = *reinterpret_cast<const float4*>(gamma + tid * 4);
  const float4 be = *reinterpret_cast<const float4*>(beta + tid * 4);
  float4 o;
  o.x = g.x * (v.x - mu) * rs + be.x;
  o.y = g.y * (v.y - mu) * rs + be.y;
  o.z = g.z * (v.z - mu) * rs + be.z;
  o.w = g.w * (v.w - mu) * rs + be.w;
  *reinterpret_cast<float4*>(C + (size_t)row * OUT_F + tid * 4) = o;
}

extern "C" void kernel_launch(void* const* d_in, const int* in_sizes, int n_in,
                              void* d_out, int out_size, void* d_ws, size_t ws_size,
                              hipStream_t stream) {
  const float* x     = (const float*)d_in[0];
  const float* cp    = (const float*)d_in[1];
  const float* W     = (const float*)d_in[2];
  const float* bias  = (const float*)d_in[3];
  const float* gamma = (const float*)d_in[4];
  const float* beta  = (const float*)d_in[5];
  float* out = (float*)d_out;

  unsigned short* Bm = (unsigned short*)d_ws;
  const size_t bBytes = (size_t)OUT_F * KP * sizeof(unsigned short);   // 24 MiB
  size_t avail = ws_size > bBytes ? ws_size - bBytes : 0;
  // per-row: 24 KiB bf16 features + 4 KiB fp32 partial
  const size_t perRow = (size_t)KP * 2 + (size_t)OUT_F * 4;
  long long fit = (long long)(avail / perRow);
  int chunk;
  if (fit >= BATCH)     chunk = BATCH;
  else if (fit >= 8192) chunk = 8192;    // 512 WGs = exactly 2 blocks/CU
  else                  chunk = (int)((fit / 256) * 256);
  if (chunk < 256) chunk = 256;

  unsigned short* Af = (unsigned short*)((char*)d_ws + bBytes);
  float* P = (float*)(Af + (size_t)chunk * KP);

  bgen<<<OUT_F, 256, 0, stream>>>(cp, W, Bm);
  for (int r0 = 0; r0 < BATCH; r0 += chunk) {
    const int rows = (BATCH - r0 < chunk) ? (BATCH - r0) : chunk;
    featgen<<<rows, 256, 0, stream>>>(x, Af, r0);
    const int nbm = rows / 256;
    gemmk<<<nbm * 16, 512, 0, stream>>>(Af, Bm, out + (size_t)r0 * OUT_F, P, nbm);
    ln_kernel<<<rows, 256, 0, stream>>>(out + (size_t)r0 * OUT_F, P, bias, gamma, beta);
  }
}

// Round 11
// 432.421 us; speedup vs baseline: 1.3661x; 1.3661x over previous
//
#include <hip/hip_runtime.h>
#include <hip/hip_bf16.h>

#define BATCH   16384
#define IN_F    1024
#define OUT_F   1024
#define KCOLS   11
#define KPL     12          // 11 basis planes + 1 x-plane (for W)
#define KP      (KPL*IN_F)  // 12288
#define KHALF   (KP/2)      // 6144 per split-K block
#define NTKH    (KHALF/64)  // 96 K-tiles of 64 per half
#define NITH    (NTKH/2)    // 48 main-loop iterations (2 K-tiles each)
#define LN_EPS  1e-5f

typedef __attribute__((ext_vector_type(8))) short short8;
typedef __attribute__((ext_vector_type(4))) float f32x4;

static __device__ __forceinline__ unsigned short f2bf(float f) {
  __hip_bfloat16 h = __float2bfloat16(f);
  return *reinterpret_cast<unsigned short*>(&h);
}
static __device__ __forceinline__ float bf2f(unsigned short u) {
  unsigned int x = ((unsigned int)u) << 16;
  return *reinterpret_cast<float*>(&x);
}

// Cox-de Boor, faithful to the reference's in-place variant.
// All denominators are compile-time constants -> multiply by folded reciprocal.
__device__ __forceinline__ void bspline_basis(float x, float bas[KCOLS]) {
  const float s = 1.0f / 11.0f;
  float kn[12];
#pragma unroll
  for (int j = 0; j < 12; ++j) kn[j] = (float)j * s;
  kn[11] = 1.0f;
#pragma unroll
  for (int j = 0; j < 11; ++j)
    bas[j] = (x >= kn[j] && x < kn[j + 1]) ? 1.0f : 0.0f;
#pragma unroll
  for (int d = 1; d <= 3; ++d) {
#pragma unroll
    for (int j = 0; j < 11 - d; ++j) {
      const float r1 = 1.0f / (kn[j + d] - kn[j]);
      const float r2 = 1.0f / (kn[j + d + 1] - kn[j + 1]);
      float a = (x - kn[j]) * r1;
      float c = (kn[j + d + 1] - x) * r2;
      bas[j] = a * bas[j] + c * bas[j + 1];
    }
  }
}

// A[localRow][k*1024 + i] (bf16): 11 basis planes + x plane.
// 2 rows/block, 8 elems/thread, 16-B stores.
__global__ __launch_bounds__(256) void featgen(const float* __restrict__ X,
                                               unsigned short* __restrict__ A,
                                               int row0) {
  const int tid = threadIdx.x;
  const int brow = blockIdx.x * 2 + (tid >> 7);
  const int i0 = (tid & 127) * 8;
  const float4 xv0 = *reinterpret_cast<const float4*>(X + (size_t)(row0 + brow) * IN_F + i0);
  const float4 xv1 = *reinterpret_cast<const float4*>(X + (size_t)(row0 + brow) * IN_F + i0 + 4);
  float xs[8] = {xv0.x, xv0.y, xv0.z, xv0.w, xv1.x, xv1.y, xv1.z, xv1.w};
  float bas[8][KCOLS];
#pragma unroll
  for (int t = 0; t < 8; ++t) bspline_basis(xs[t], bas[t]);
  unsigned short* outp = A + (size_t)brow * KP + i0;
#pragma unroll
  for (int k = 0; k < KCOLS; ++k) {
    unsigned short u[8];
#pragma unroll
    for (int t = 0; t < 8; ++t) u[t] = f2bf(bas[t][k]);
    *reinterpret_cast<short8*>(outp + (size_t)k * IN_F) = *reinterpret_cast<short8*>(u);
  }
  unsigned short u[8];
#pragma unroll
  for (int t = 0; t < 8; ++t) u[t] = f2bf(xs[t]);
  *reinterpret_cast<short8*>(outp + (size_t)KCOLS * IN_F) = *reinterpret_cast<short8*>(u);
}

// Bmat[o][k*1024 + i] (bf16): cp planes + W plane.
__global__ __launch_bounds__(256) void bgen(const float* __restrict__ CP,
                                            const float* __restrict__ W,
                                            unsigned short* __restrict__ Bm) {
  const int o = blockIdx.x;
  const int i0 = threadIdx.x * 4;
  unsigned short* outp = Bm + (size_t)o * KP + i0;
#pragma unroll
  for (int k = 0; k < KCOLS; ++k) {
    ushort4 u;
    u.x = f2bf(CP[((size_t)o * IN_F + i0 + 0) * KCOLS + k]);
    u.y = f2bf(CP[((size_t)o * IN_F + i0 + 1) * KCOLS + k]);
    u.z = f2bf(CP[((size_t)o * IN_F + i0 + 2) * KCOLS + k]);
    u.w = f2bf(CP[((size_t)o * IN_F + i0 + 3) * KCOLS + k]);
    *reinterpret_cast<ushort4*>(outp + (size_t)k * IN_F) = u;
  }
  ushort4 u;
  u.x = f2bf(W[(size_t)o * IN_F + i0 + 0]);
  u.y = f2bf(W[(size_t)o * IN_F + i0 + 1]);
  u.z = f2bf(W[(size_t)o * IN_F + i0 + 2]);
  u.w = f2bf(W[(size_t)o * IN_F + i0 + 3]);
  *reinterpret_cast<ushort4*>(outp + (size_t)KCOLS * IN_F) = u;
}

// ---- 256x256 single-barrier split-K GEMM (r6 schedule, bf16 partial out) ----
// ks=0 blocks -> Cb0, ks=1 blocks -> Cb1 (both bf16 in ws). Grid = nbm*8;
// 8192 rows -> 256 WGs. 512 thr = 8 waves (2M x 4N); BK=64; LDS 128 KiB dbuf.
// ONE trailing barrier per phase; WAITV(4) at P4/P8 (counted, never 0 mid-loop).

#define BAR()    __builtin_amdgcn_s_barrier()
#define SCHED0() __builtin_amdgcn_sched_barrier(0)
#define WAITV(N) asm volatile("s_waitcnt vmcnt(" #N ")" ::: "memory")

__global__ __launch_bounds__(512, 2) void gemm8p(const unsigned short* __restrict__ A,
                                                 const unsigned short* __restrict__ Bm,
                                                 unsigned short* __restrict__ Cb0,
                                                 unsigned short* __restrict__ Cb1, int nbm) {
  __shared__ unsigned short lds[2][2][2][128 * 64];  // [buf][A=0/B=1][half][...]
  const int tid  = (int)threadIdx.x;
  const int lane = tid & 63;
  const int w    = tid >> 6;
  const int wm   = w >> 2;       // 0..1
  const int wn   = w & 3;        // 0..3

  // XCD-aware bijective swizzle; per-XCD chunk = {4 bm} x {2 ks} x {4 bn}.
  const int nwg = nbm * 8;
  const int cpx = nwg >> 3;
  const int bid = (int)blockIdx.x;
  const int swz = (bid & 7) * cpx + (bid >> 3);
  const int bn = swz & 3;
  const int ks = (swz >> 2) & 1;
  const int bm = swz >> 3;
  const size_t koff = (size_t)ks * KHALF;
  unsigned short* __restrict__ C = ks ? Cb1 : Cb0;

  // staging: one issue = 512 thr x 16 B = 64 rows x 64 cols.
  // Linear LDS dest; source col carries the inverse swizzle c ^ (row&7).
  const int srow = (w << 3) + (lane >> 3);            // 0..63 within one issue
  const int scol = ((lane & 7) ^ (lane >> 3)) << 3;   // element col, swizzled
  const unsigned short* aB = A  + (size_t)(bm * 256 + srow) * KP + koff + scol;
  const unsigned short* bB = Bm + (size_t)(bn * 256 + srow) * KP + koff + scol;

#define STAGE(T, AB, H, BUF)                                                          \
  do {                                                                                \
    if ((T) < NTKH) {                                                                 \
      const unsigned short* g_ = ((AB) ? bB : aB) + (size_t)(H) * 128 * KP + (size_t)(T) * 64; \
      unsigned short* l_ = &lds[BUF][AB][H][w * 512];                                 \
      __builtin_amdgcn_global_load_lds((const __attribute__((address_space(1))) void*)g_,       \
                                       (__attribute__((address_space(3))) void*)l_, 16, 0, 0);  \
      __builtin_amdgcn_global_load_lds((const __attribute__((address_space(1))) void*)(g_ + (size_t)64 * KP), \
                                       (__attribute__((address_space(3))) void*)(l_ + 4096), 16, 0, 0); \
    }                                                                                 \
  } while (0)

  // fragment reads (ds_read_b128, swizzled col)
  const int fr = lane & 15;
  const int g4 = lane >> 4;
  const int s7 = lane & 7;
  const int col0 = ((g4 ^ s7) << 3);        // kk=0 (elements)
  const int col1 = (((4 + g4) ^ s7) << 3);  // kk=1
  const unsigned short* aH[2] = {&lds[0][0][wm][0], &lds[1][0][wm][0]};
  const unsigned short* bH[2] = {&lds[0][1][wn >> 1][0], &lds[1][1][wn >> 1][0]};
  const int brow0 = (wn & 1) * 64;

  short8 aF[4][2], bF0[2][2], bF1[2][2];
  f32x4 acc[8][4] = {};

#define LOADA(MB, BUF)                                                         \
  do {                                                                         \
    _Pragma("unroll") for (int m_ = 0; m_ < 4; ++m_) {                         \
      const unsigned short* p_ = aH[BUF] + ((MB) + m_) * 1024 + fr * 64;       \
      aF[m_][0] = *reinterpret_cast<const short8*>(p_ + col0);                 \
      aF[m_][1] = *reinterpret_cast<const short8*>(p_ + col1);                 \
    }                                                                          \
  } while (0)

#define LOADB(DST, NB, BUF)                                                    \
  do {                                                                         \
    _Pragma("unroll") for (int n_ = 0; n_ < 2; ++n_) {                         \
      const unsigned short* p_ = bH[BUF] + (brow0 + ((NB) + n_) * 16 + fr) * 64; \
      DST[n_][0] = *reinterpret_cast<const short8*>(p_ + col0);                \
      DST[n_][1] = *reinterpret_cast<const short8*>(p_ + col1);                \
    }                                                                          \
  } while (0)

#define MFMAQ(MB, NB, BF)                                                      \
  do {                                                                         \
    __builtin_amdgcn_s_setprio(1);                                             \
    _Pragma("unroll") for (int m_ = 0; m_ < 4; ++m_)                           \
    _Pragma("unroll") for (int n_ = 0; n_ < 2; ++n_)                           \
    _Pragma("unroll") for (int kk_ = 0; kk_ < 2; ++kk_)                        \
      acc[(MB) + m_][(NB) + n_] = __builtin_amdgcn_mfma_f32_16x16x32_bf16(     \
          aF[m_][kk_], BF[n_][kk_], acc[(MB) + m_][(NB) + n_], 0, 0, 0);       \
    __builtin_amdgcn_s_setprio(0);                                             \
  } while (0)

  // prologue: tile0 (B0,B1,A0,A1) + tile1 (B0,B1); drain to 4 outstanding.
  STAGE(0, 0, 0, 0); STAGE(0, 0, 1, 0);
  STAGE(0, 1, 0, 0); STAGE(0, 1, 1, 0);
  STAGE(1, 1, 0, 1); STAGE(1, 1, 1, 1);
  WAITV(4);
  BAR();

#pragma unroll 1
  for (int j = 0; j < NITH; ++j) {
    const int tA = 2 * j + 1, tB2 = 2 * j + 2, tB3 = 2 * j + 3;
    // P1: quad(m0-3,n0-1) of tile 2j (buf0); stage A-half0 of 2j+1 -> buf1
    LOADA(0, 0); LOADB(bF0, 0, 0);
    STAGE(tA, 0, 0, 1);
    MFMAQ(0, 0, bF0);
    SCHED0(); BAR();
    // P2: quad(m0-3,n2-3); stage A-half1 of 2j+1
    LOADB(bF1, 2, 0);
    STAGE(tA, 0, 1, 1);
    MFMAQ(0, 2, bF1);
    SCHED0(); BAR();
    // P3: quad(m4-7,n0-1); stage B-half0 of 2j+2 -> buf0
    LOADA(4, 0);
    STAGE(tB2, 1, 0, 0);
    MFMAQ(4, 0, bF0);
    SCHED0(); BAR();
    // P4: quad(m4-7,n2-3); stage B-half1 of 2j+2; counted vmcnt for buf1 tile
    STAGE(tB2, 1, 1, 0);
    MFMAQ(4, 2, bF1);
    if (j < NITH - 1) { WAITV(4); } else { WAITV(0); }
    SCHED0(); BAR();
    // P5: tile 2j+1 (buf1) quad(m0-3,n0-1); stage A-half0 of 2j+2 -> buf0
    LOADA(0, 1); LOADB(bF0, 0, 1);
    STAGE(tB2, 0, 0, 0);
    MFMAQ(0, 0, bF0);
    SCHED0(); BAR();
    // P6: quad(m0-3,n2-3); stage A-half1 of 2j+2
    LOADB(bF1, 2, 1);
    STAGE(tB2, 0, 1, 0);
    MFMAQ(0, 2, bF1);
    SCHED0(); BAR();
    // P7: quad(m4-7,n0-1); stage B-half0 of 2j+3 -> buf1
    LOADA(4, 1);
    STAGE(tB3, 1, 0, 1);
    MFMAQ(4, 0, bF0);
    SCHED0(); BAR();
    // P8: quad(m4-7,n2-3); stage B-half1 of 2j+3; counted vmcnt for next buf0
    STAGE(tB3, 1, 1, 1);
    MFMAQ(4, 2, bF1);
    if (j < NITH - 1) { WAITV(4); }
    SCHED0(); BAR();
  }

  // C/D layout (verified m89/m91): col = lane&15, row = (lane>>4)*4 + reg
  const size_t r0 = (size_t)bm * 256 + wm * 128 + (lane >> 4) * 4;
  const int c0 = bn * 256 + wn * 64 + fr;
#pragma unroll
  for (int m = 0; m < 8; ++m)
#pragma unroll
    for (int n = 0; n < 4; ++n)
#pragma unroll
      for (int r = 0; r < 4; ++r)
        C[(r0 + m * 16 + r) * OUT_F + (c0 + n * 16)] = f2bf(acc[m][n][r]);
}

// Row LayerNorm over bf16(C0)+bf16(C1)+bias, written fp32 to Out.
__global__ __launch_bounds__(256) void ln_kernel(const unsigned short* __restrict__ C0,
                                                 const unsigned short* __restrict__ C1,
                                                 float* __restrict__ Out,
                                                 const float* __restrict__ bias,
                                                 const float* __restrict__ gamma,
                                                 const float* __restrict__ beta) {
  const int row = blockIdx.x;
  const int tid = threadIdx.x;
  const ushort4 a = *reinterpret_cast<const ushort4*>(C0 + (size_t)row * OUT_F + tid * 4);
  const ushort4 b = *reinterpret_cast<const ushort4*>(C1 + (size_t)row * OUT_F + tid * 4);
  const float4 bb = *reinterpret_cast<const float4*>(bias + tid * 4);
  float4 v;
  v.x = bf2f(a.x) + bf2f(b.x) + bb.x;
  v.y = bf2f(a.y) + bf2f(b.y) + bb.y;
  v.z = bf2f(a.z) + bf2f(b.z) + bb.z;
  v.w = bf2f(a.w) + bf2f(b.w) + bb.w;
  float s = v.x + v.y + v.z + v.w;
  float q = v.x * v.x + v.y * v.y + v.z * v.z + v.w * v.w;
#pragma unroll
  for (int off = 32; off > 0; off >>= 1) {
    s += __shfl_down(s, off);
    q += __shfl_down(q, off);
  }
  __shared__ float red[8];
  const int wave = tid >> 6, lane = tid & 63;
  if (lane == 0) { red[wave] = s; red[4 + wave] = q; }
  __syncthreads();
  s = red[0] + red[1] + red[2] + red[3];
  q = red[4] + red[5] + red[6] + red[7];
  const float mu = s * (1.0f / OUT_F);
  const float var = q * (1.0f / OUT_F) - mu * mu;
  const float rs = rsqrtf(var + LN_EPS);
  const float4 g = *reinterpret_cast<const float4*>(gamma + tid * 4);
  const float4 be = *reinterpret_cast<const float4*>(beta + tid * 4);
  float4 o;
  o.x = g.x * (v.x - mu) * rs + be.x;
  o.y = g.y * (v.y - mu) * rs + be.y;
  o.z = g.z * (v.z - mu) * rs + be.z;
  o.w = g.w * (v.w - mu) * rs + be.w;
  *reinterpret_cast<float4*>(Out + (size_t)row * OUT_F + tid * 4) = o;
}

extern "C" void kernel_launch(void* const* d_in, const int* in_sizes, int n_in,
                              void* d_out, int out_size, void* d_ws, size_t ws_size,
                              hipStream_t stream) {
  const float* x     = (const float*)d_in[0];
  const float* cp    = (const float*)d_in[1];
  const float* W     = (const float*)d_in[2];
  const float* bias  = (const float*)d_in[3];
  const float* gamma = (const float*)d_in[4];
  const float* beta  = (const float*)d_in[5];
  float* out = (float*)d_out;

  unsigned short* Bm = (unsigned short*)d_ws;
  const size_t bBytes = (size_t)OUT_F * KP * sizeof(unsigned short);   // 24 MiB
  size_t avail = ws_size > bBytes ? ws_size - bBytes : 0;
  // per-row: 24 KiB bf16 features + 2x2 KiB bf16 partials
  const size_t perRow = (size_t)KP * 2 + (size_t)OUT_F * 4;
  long long fit = (long long)(avail / perRow);
  int chunk;
  if (fit >= BATCH)     chunk = BATCH;
  else if (fit >= 8192) chunk = 8192;    // 256 WGs = exact full fill
  else                  chunk = (int)((fit / 256) * 256);
  if (chunk < 256) chunk = 256;

  unsigned short* Af  = (unsigned short*)((char*)d_ws + bBytes);
  unsigned short* Cb0 = Af + (size_t)chunk * KP;
  unsigned short* Cb1 = Cb0 + (size_t)chunk * OUT_F;

  bgen<<<OUT_F, 256, 0, stream>>>(cp, W, Bm);
  for (int r0 = 0; r0 < BATCH; r0 += chunk) {
    const int rows = (BATCH - r0 < chunk) ? (BATCH - r0) : chunk;
    featgen<<<rows / 2, 256, 0, stream>>>(x, Af, r0);
    const int nbm = rows / 256;
    gemm8p<<<nbm * 8, 512, 0, stream>>>(Af, Bm, Cb0, Cb1, nbm);
    ln_kernel<<<rows, 256, 0, stream>>>(Cb0, Cb1, out + (size_t)r0 * OUT_F,
                                        bias, gamma, beta);
  }
}

// Round 12
// 427.041 us; speedup vs baseline: 1.3833x; 1.0126x over previous
//
#include <hip/hip_runtime.h>
#include <hip/hip_bf16.h>

#define BATCH   16384
#define IN_F    1024
#define OUT_F   1024
#define KCOLS   11
#define KPL     12          // 11 basis planes + 1 x-plane (for W)
#define KP      (KPL*IN_F)  // 12288
#define KHALF   (KP/2)      // 6144 per split-K block
#define NTKH    (KHALF/64)  // 96 K-tiles of 64 per half
#define NITH    (NTKH/2)    // 48 main-loop iterations (2 K-tiles each)
#define LN_EPS  1e-5f

typedef __attribute__((ext_vector_type(8))) short short8;
typedef __attribute__((ext_vector_type(4))) float f32x4;

static __device__ __forceinline__ unsigned short f2bf(float f) {
  __hip_bfloat16 h = __float2bfloat16(f);
  return *reinterpret_cast<unsigned short*>(&h);
}
static __device__ __forceinline__ float bf2f(unsigned short u) {
  unsigned int x = ((unsigned int)u) << 16;
  return *reinterpret_cast<float*>(&x);
}

// Cox-de Boor, faithful to the reference's in-place variant.
// All denominators are compile-time constants -> multiply by folded reciprocal.
__device__ __forceinline__ void bspline_basis(float x, float bas[KCOLS]) {
  const float s = 1.0f / 11.0f;
  float kn[12];
#pragma unroll
  for (int j = 0; j < 12; ++j) kn[j] = (float)j * s;
  kn[11] = 1.0f;
#pragma unroll
  for (int j = 0; j < 11; ++j)
    bas[j] = (x >= kn[j] && x < kn[j + 1]) ? 1.0f : 0.0f;
#pragma unroll
  for (int d = 1; d <= 3; ++d) {
#pragma unroll
    for (int j = 0; j < 11 - d; ++j) {
      const float r1 = 1.0f / (kn[j + d] - kn[j]);
      const float r2 = 1.0f / (kn[j + d + 1] - kn[j + 1]);
      float a = (x - kn[j]) * r1;
      float c = (kn[j + d + 1] - x) * r2;
      bas[j] = a * bas[j] + c * bas[j + 1];
    }
  }
}

// A[localRow][k*1024 + i] (bf16): 11 basis planes + x plane.
// 2 rows/block, 8 elems/thread, 16-B stores.
__global__ __launch_bounds__(256) void featgen(const float* __restrict__ X,
                                               unsigned short* __restrict__ A,
                                               int row0) {
  const int tid = threadIdx.x;
  const int brow = blockIdx.x * 2 + (tid >> 7);
  const int i0 = (tid & 127) * 8;
  const float4 xv0 = *reinterpret_cast<const float4*>(X + (size_t)(row0 + brow) * IN_F + i0);
  const float4 xv1 = *reinterpret_cast<const float4*>(X + (size_t)(row0 + brow) * IN_F + i0 + 4);
  float xs[8] = {xv0.x, xv0.y, xv0.z, xv0.w, xv1.x, xv1.y, xv1.z, xv1.w};
  float bas[8][KCOLS];
#pragma unroll
  for (int t = 0; t < 8; ++t) bspline_basis(xs[t], bas[t]);
  unsigned short* outp = A + (size_t)brow * KP + i0;
#pragma unroll
  for (int k = 0; k < KCOLS; ++k) {
    unsigned short u[8];
#pragma unroll
    for (int t = 0; t < 8; ++t) u[t] = f2bf(bas[t][k]);
    *reinterpret_cast<short8*>(outp + (size_t)k * IN_F) = *reinterpret_cast<short8*>(u);
  }
  unsigned short u[8];
#pragma unroll
  for (int t = 0; t < 8; ++t) u[t] = f2bf(xs[t]);
  *reinterpret_cast<short8*>(outp + (size_t)KCOLS * IN_F) = *reinterpret_cast<short8*>(u);
}

// Bmat[o][k*1024 + i] (bf16): cp planes + W plane.
// Thread reads its 44 consecutive CP floats as 11 aligned float4s.
__global__ __launch_bounds__(256) void bgen(const float* __restrict__ CP,
                                            const float* __restrict__ W,
                                            unsigned short* __restrict__ Bm) {
  const int o = blockIdx.x;
  const int i0 = threadIdx.x * 4;
  // (o*1024 + i0)*11 floats from base; offset bytes = multiple of 176 -> 16-aligned
  const float4* src = reinterpret_cast<const float4*>(CP + ((size_t)o * IN_F + i0) * KCOLS);
  float4 c[11];
#pragma unroll
  for (int q = 0; q < 11; ++q) c[q] = src[q];
  const float* cf = reinterpret_cast<const float*>(c);  // cf[e*11 + k], statically indexed
  unsigned short* outp = Bm + (size_t)o * KP + i0;
#pragma unroll
  for (int k = 0; k < KCOLS; ++k) {
    ushort4 u;
    u.x = f2bf(cf[0 * KCOLS + k]);
    u.y = f2bf(cf[1 * KCOLS + k]);
    u.z = f2bf(cf[2 * KCOLS + k]);
    u.w = f2bf(cf[3 * KCOLS + k]);
    *reinterpret_cast<ushort4*>(outp + (size_t)k * IN_F) = u;
  }
  const float4 wv = *reinterpret_cast<const float4*>(W + (size_t)o * IN_F + i0);
  ushort4 u;
  u.x = f2bf(wv.x); u.y = f2bf(wv.y); u.z = f2bf(wv.z); u.w = f2bf(wv.w);
  *reinterpret_cast<ushort4*>(outp + (size_t)KCOLS * IN_F) = u;
}

// ---- 256x256 single-barrier split-K GEMM (r6 schedule, bf16 partial out) ----
#define BAR()    __builtin_amdgcn_s_barrier()
#define SCHED0() __builtin_amdgcn_sched_barrier(0)
#define WAITV(N) asm volatile("s_waitcnt vmcnt(" #N ")" ::: "memory")

__global__ __launch_bounds__(512, 2) void gemm8p(const unsigned short* __restrict__ A,
                                                 const unsigned short* __restrict__ Bm,
                                                 unsigned short* __restrict__ Cb0,
                                                 unsigned short* __restrict__ Cb1, int nbm) {
  __shared__ unsigned short lds[2][2][2][128 * 64];  // [buf][A=0/B=1][half][...]
  const int tid  = (int)threadIdx.x;
  const int lane = tid & 63;
  const int w    = tid >> 6;
  const int wm   = w >> 2;       // 0..1
  const int wn   = w & 3;        // 0..3

  // XCD-aware bijective swizzle; per-XCD chunk = {4 bm} x {2 ks} x {4 bn}.
  const int nwg = nbm * 8;
  const int cpx = nwg >> 3;
  const int bid = (int)blockIdx.x;
  const int swz = (bid & 7) * cpx + (bid >> 3);
  const int bn = swz & 3;
  const int ks = (swz >> 2) & 1;
  const int bm = swz >> 3;
  const size_t koff = (size_t)ks * KHALF;
  unsigned short* __restrict__ C = ks ? Cb1 : Cb0;

  // staging: one issue = 512 thr x 16 B = 64 rows x 64 cols.
  // Linear LDS dest; source col carries the inverse swizzle c ^ (row&7).
  const int srow = (w << 3) + (lane >> 3);            // 0..63 within one issue
  const int scol = ((lane & 7) ^ (lane >> 3)) << 3;   // element col, swizzled
  const unsigned short* aB = A  + (size_t)(bm * 256 + srow) * KP + koff + scol;
  const unsigned short* bB = Bm + (size_t)(bn * 256 + srow) * KP + koff + scol;

#define STAGE(T, AB, H, BUF)                                                          \
  do {                                                                                \
    if ((T) < NTKH) {                                                                 \
      const unsigned short* g_ = ((AB) ? bB : aB) + (size_t)(H) * 128 * KP + (size_t)(T) * 64; \
      unsigned short* l_ = &lds[BUF][AB][H][w * 512];                                 \
      __builtin_amdgcn_global_load_lds((const __attribute__((address_space(1))) void*)g_,       \
                                       (__attribute__((address_space(3))) void*)l_, 16, 0, 0);  \
      __builtin_amdgcn_global_load_lds((const __attribute__((address_space(1))) void*)(g_ + (size_t)64 * KP), \
                                       (__attribute__((address_space(3))) void*)(l_ + 4096), 16, 0, 0); \
    }                                                                                 \
  } while (0)

  // fragment reads (ds_read_b128, swizzled col)
  const int fr = lane & 15;
  const int g4 = lane >> 4;
  const int s7 = lane & 7;
  const int col0 = ((g4 ^ s7) << 3);        // kk=0 (elements)
  const int col1 = (((4 + g4) ^ s7) << 3);  // kk=1
  const unsigned short* aH[2] = {&lds[0][0][wm][0], &lds[1][0][wm][0]};
  const unsigned short* bH[2] = {&lds[0][1][wn >> 1][0], &lds[1][1][wn >> 1][0]};
  const int brow0 = (wn & 1) * 64;

  short8 aF[4][2], bF0[2][2], bF1[2][2];
  f32x4 acc[8][4] = {};

#define LOADA(MB, BUF)                                                         \
  do {                                                                         \
    _Pragma("unroll") for (int m_ = 0; m_ < 4; ++m_) {                         \
      const unsigned short* p_ = aH[BUF] + ((MB) + m_) * 1024 + fr * 64;       \
      aF[m_][0] = *reinterpret_cast<const short8*>(p_ + col0);                 \
      aF[m_][1] = *reinterpret_cast<const short8*>(p_ + col1);                 \
    }                                                                          \
  } while (0)

#define LOADB(DST, NB, BUF)                                                    \
  do {                                                                         \
    _Pragma("unroll") for (int n_ = 0; n_ < 2; ++n_) {                         \
      const unsigned short* p_ = bH[BUF] + (brow0 + ((NB) + n_) * 16 + fr) * 64; \
      DST[n_][0] = *reinterpret_cast<const short8*>(p_ + col0);                \
      DST[n_][1] = *reinterpret_cast<const short8*>(p_ + col1);                \
    }                                                                          \
  } while (0)

#define MFMAQ(MB, NB, BF)                                                      \
  do {                                                                         \
    __builtin_amdgcn_s_setprio(1);                                             \
    _Pragma("unroll") for (int m_ = 0; m_ < 4; ++m_)                           \
    _Pragma("unroll") for (int n_ = 0; n_ < 2; ++n_)                           \
    _Pragma("unroll") for (int kk_ = 0; kk_ < 2; ++kk_)                        \
      acc[(MB) + m_][(NB) + n_] = __builtin_amdgcn_mfma_f32_16x16x32_bf16(     \
          aF[m_][kk_], BF[n_][kk_], acc[(MB) + m_][(NB) + n_], 0, 0, 0);       \
    __builtin_amdgcn_s_setprio(0);                                             \
  } while (0)

  // prologue: tile0 (B0,B1,A0,A1) + tile1 (B0,B1); drain to 4 outstanding.
  STAGE(0, 0, 0, 0); STAGE(0, 0, 1, 0);
  STAGE(0, 1, 0, 0); STAGE(0, 1, 1, 0);
  STAGE(1, 1, 0, 1); STAGE(1, 1, 1, 1);
  WAITV(4);
  BAR();

#pragma unroll 1
  for (int j = 0; j < NITH; ++j) {
    const int tA = 2 * j + 1, tB2 = 2 * j + 2, tB3 = 2 * j + 3;
    // P1: quad(m0-3,n0-1) of tile 2j (buf0); stage A-half0 of 2j+1 -> buf1
    LOADA(0, 0); LOADB(bF0, 0, 0);
    STAGE(tA, 0, 0, 1);
    MFMAQ(0, 0, bF0);
    SCHED0(); BAR();
    // P2: quad(m0-3,n2-3); stage A-half1 of 2j+1
    LOADB(bF1, 2, 0);
    STAGE(tA, 0, 1, 1);
    MFMAQ(0, 2, bF1);
    SCHED0(); BAR();
    // P3: quad(m4-7,n0-1); stage B-half0 of 2j+2 -> buf0
    LOADA(4, 0);
    STAGE(tB2, 1, 0, 0);
    MFMAQ(4, 0, bF0);
    SCHED0(); BAR();
    // P4: quad(m4-7,n2-3); stage B-half1 of 2j+2; counted vmcnt for buf1 tile
    STAGE(tB2, 1, 1, 0);
    MFMAQ(4, 2, bF1);
    if (j < NITH - 1) { WAITV(4); } else { WAITV(0); }
    SCHED0(); BAR();
    // P5: tile 2j+1 (buf1) quad(m0-3,n0-1); stage A-half0 of 2j+2 -> buf0
    LOADA(0, 1); LOADB(bF0, 0, 1);
    STAGE(tB2, 0, 0, 0);
    MFMAQ(0, 0, bF0);
    SCHED0(); BAR();
    // P6: quad(m0-3,n2-3); stage A-half1 of 2j+2
    LOADB(bF1, 2, 1);
    STAGE(tB2, 0, 1, 0);
    MFMAQ(0, 2, bF1);
    SCHED0(); BAR();
    // P7: quad(m4-7,n0-1); stage B-half0 of 2j+3 -> buf1
    LOADA(4, 1);
    STAGE(tB3, 1, 0, 1);
    MFMAQ(4, 0, bF0);
    SCHED0(); BAR();
    // P8: quad(m4-7,n2-3); stage B-half1 of 2j+3; counted vmcnt for next buf0
    STAGE(tB3, 1, 1, 1);
    MFMAQ(4, 2, bF1);
    if (j < NITH - 1) { WAITV(4); }
    SCHED0(); BAR();
  }

  // C/D layout (verified m89/m91): col = lane&15, row = (lane>>4)*4 + reg
  const size_t r0 = (size_t)bm * 256 + wm * 128 + (lane >> 4) * 4;
  const int c0 = bn * 256 + wn * 64 + fr;
#pragma unroll
  for (int m = 0; m < 8; ++m)
#pragma unroll
    for (int n = 0; n < 4; ++n)
#pragma unroll
      for (int r = 0; r < 4; ++r)
        C[(r0 + m * 16 + r) * OUT_F + (c0 + n * 16)] = f2bf(acc[m][n][r]);
}

// Row LayerNorm over bf16(C0)+bf16(C1)+bias -> fp32 Out.
// 2 rows/block, 8 cols/thread (16-B loads); per-row reduce = 2 waves + LDS pair.
__global__ __launch_bounds__(256) void ln_kernel(const unsigned short* __restrict__ C0,
                                                 const unsigned short* __restrict__ C1,
                                                 float* __restrict__ Out,
                                                 const float* __restrict__ bias,
                                                 const float* __restrict__ gamma,
                                                 const float* __restrict__ beta) {
  const int tid = threadIdx.x;
  const int half = tid >> 7;                 // which row of the pair
  const int row = blockIdx.x * 2 + half;
  const int t = tid & 127;
  const int c0i = t * 8;
  const short8 a = *reinterpret_cast<const short8*>(C0 + (size_t)row * OUT_F + c0i);
  const short8 b = *reinterpret_cast<const short8*>(C1 + (size_t)row * OUT_F + c0i);
  float v[8];
#pragma unroll
  for (int e = 0; e < 8; ++e)
    v[e] = bf2f((unsigned short)a[e]) + bf2f((unsigned short)b[e]) + bias[c0i + e];
  float s = 0.f, q = 0.f;
#pragma unroll
  for (int e = 0; e < 8; ++e) { s += v[e]; q += v[e] * v[e]; }
#pragma unroll
  for (int off = 32; off > 0; off >>= 1) {
    s += __shfl_down(s, off);
    q += __shfl_down(q, off);
  }
  __shared__ float red[8];
  const int wave = tid >> 6, lane = tid & 63;
  if (lane == 0) { red[wave] = s; red[4 + wave] = q; }
  __syncthreads();
  s = red[half * 2] + red[half * 2 + 1];
  q = red[4 + half * 2] + red[4 + half * 2 + 1];
  const float mu = s * (1.0f / OUT_F);
  const float var = q * (1.0f / OUT_F) - mu * mu;
  const float rs = rsqrtf(var + LN_EPS);
  float o[8];
#pragma unroll
  for (int e = 0; e < 8; ++e)
    o[e] = gamma[c0i + e] * (v[e] - mu) * rs + beta[c0i + e];
  float* dst = Out + (size_t)row * OUT_F + c0i;
  *reinterpret_cast<float4*>(dst)     = make_float4(o[0], o[1], o[2], o[3]);
  *reinterpret_cast<float4*>(dst + 4) = make_float4(o[4], o[5], o[6], o[7]);
}

extern "C" void kernel_launch(void* const* d_in, const int* in_sizes, int n_in,
                              void* d_out, int out_size, void* d_ws, size_t ws_size,
                              hipStream_t stream) {
  const float* x     = (const float*)d_in[0];
  const float* cp    = (const float*)d_in[1];
  const float* W     = (const float*)d_in[2];
  const float* bias  = (const float*)d_in[3];
  const float* gamma = (const float*)d_in[4];
  const float* beta  = (const float*)d_in[5];
  float* out = (float*)d_out;

  unsigned short* Bm = (unsigned short*)d_ws;
  const size_t bBytes = (size_t)OUT_F * KP * sizeof(unsigned short);   // 24 MiB
  size_t avail = ws_size > bBytes ? ws_size - bBytes : 0;
  // per-row: 24 KiB bf16 features + 2x2 KiB bf16 partials
  const size_t perRow = (size_t)KP * 2 + (size_t)OUT_F * 4;
  long long fit = (long long)(avail / perRow);
  int chunk;
  if (fit >= BATCH)     chunk = BATCH;
  else if (fit >= 8192) chunk = 8192;    // 256 WGs = exact full fill
  else                  chunk = (int)((fit / 256) * 256);
  if (chunk < 256) chunk = 256;

  unsigned short* Af  = (unsigned short*)((char*)d_ws + bBytes);
  unsigned short* Cb0 = Af + (size_t)chunk * KP;
  unsigned short* Cb1 = Cb0 + (size_t)chunk * OUT_F;

  bgen<<<OUT_F, 256, 0, stream>>>(cp, W, Bm);
  for (int r0 = 0; r0 < BATCH; r0 += chunk) {
    const int rows = (BATCH - r0 < chunk) ? (BATCH - r0) : chunk;
    featgen<<<rows / 2, 256, 0, stream>>>(x, Af, r0);
    const int nbm = rows / 256;
    gemm8p<<<nbm * 8, 512, 0, stream>>>(Af, Bm, Cb0, Cb1, nbm);
    ln_kernel<<<rows / 2, 256, 0, stream>>>(Cb0, Cb1, out + (size_t)r0 * OUT_F,
                                            bias, gamma, beta);
  }
}